// Round 13
// baseline (98.982 us; speedup 1.0000x reference)
//
#include <hip/hip_runtime.h>

typedef __attribute__((ext_vector_type(8))) short short8;
typedef __attribute__((ext_vector_type(4))) float f32x4;

#define MFMA(a, b, c) __builtin_amdgcn_mfma_f32_16x16x32_bf16((a), (b), (c), 0, 0, 0)

#define S_LEN 1024
#define DM 1024
#define NHEADS 16
#define HD 64
#define NBH 64          // B * NHEADS = 4 * 16
#define MAXPOS 4096

__device__ __forceinline__ ushort f2bf(float f) {
    unsigned u = __builtin_bit_cast(unsigned, f);
    u += 0x7fffu + ((u >> 16) & 1u);
    return (ushort)(u >> 16);
}
__device__ __forceinline__ float bf2f(ushort h) {
    return __builtin_bit_cast(float, (unsigned)h << 16);
}

// async global->LDS, 16B per lane. LDS dest must be base + lane*16 linear.
__device__ __forceinline__ void gload16(const ushort* g, ushort* l) {
    __builtin_amdgcn_global_load_lds(
        (const __attribute__((address_space(1))) unsigned int*)g,
        (__attribute__((address_space(3))) unsigned int*)l, 16, 0, 0);
}

// ------- fp32 -> bf16 conversion (3 tensors) + RoPE table, one launch -------
__global__ __launch_bounds__(256) void k_cvt3(const float4* __restrict__ hs,
                                              const float4* __restrict__ wqkv,
                                              const float4* __restrict__ wout,
                                              ushort4* __restrict__ hsB,
                                              ushort4* __restrict__ wqkvB,
                                              ushort4* __restrict__ woutB,
                                              float* __restrict__ tab) {
    int id = blockIdx.x * 256 + threadIdx.x;
    if (id < 2097152) {
        const float4* src;
        ushort4* dst;
        int off;
        if (id < 1048576)      { src = hs;   dst = hsB;   off = id; }
        else if (id < 1835008) { src = wqkv; dst = wqkvB; off = id - 1048576; }
        else                   { src = wout; dst = woutB; off = id - 1835008; }
        float4 v = src[off];
        ushort4 o;
        o.x = f2bf(v.x); o.y = f2bf(v.y); o.z = f2bf(v.z); o.w = f2bf(v.w);
        dst[off] = o;
    } else {
        int t = id - 2097152;             // 0..131071 = 4096 pos x 32 freq
        int p = t >> 5, i = t & 31;
        float inv = powf(10000.f, -(float)(2 * i) / 64.f);
        float th = (float)p * inv;
        float s, c;
        sincosf(th, &s, &c);
        tab[2 * t] = c;
        tab[2 * t + 1] = s;
    }
}

// ---------------- GEMM1: 256x256 tile, 8 waves, phase-split ring ------------
// qkv = hs @ Wqkv^T fused with RoPE/head-split/V-transpose epilogue.
// Ring (verified R11): BK=32, 4 LDS bufs (128 KB), stage 3 K-tiles ahead,
// vmcnt(8/4/0) ladder at each K-tile boundary.
// NEW (T3+T4 proper): per K-tile, TWO double-barrier phases:
//   {ds_read subtile [+stage] ; s_barrier ; lgkmcnt(0)+sched_barrier ;
//    setprio(1) 16 MFMA setprio(0) ; s_barrier}
// Safety: stage at phase 0 targets buf (t+3)&3 == (t-1)&3 whose last reads
// completed before this K-tile's boundary barrier (lgkmcnt(0) precedes the
// prior MFMAs which precede the barrier). Data-readiness: vmcnt ladder +
// boundary barrier certify buf[t] staged by ALL threads before phase-0 reads.
__global__ __launch_bounds__(512, 2) void k_gemm256(
    const ushort* __restrict__ A, const ushort* __restrict__ BT,
    const int* __restrict__ pos, const float* __restrict__ tab,
    ushort* __restrict__ Qh, ushort* __restrict__ Kh, ushort* __restrict__ Vt) {
    __shared__ __align__(16) ushort SH[4 * 16384];   // 4 bufs x (A 256x32 | B 256x32) = 128 KB
    const int K = 1024;
    const int tid = threadIdx.x;                 // 0..511
    const int lane = tid & 63, wave = tid >> 6;  // 8 waves
    const int wr = wave >> 2, wc = wave & 3;     // 2 x 4
    const int l15 = lane & 15, lhi = lane >> 4;
    const int bx = blockIdx.x % 12, by = blockIdx.x / 12;
    const int m0 = by << 8, n0 = bx << 8;
    const int fcol = ((lhi ^ ((l15 & 3) ^ ((l15 >> 2) & 3)))) << 3;

    f32x4 acc[8][4];
#pragma unroll
    for (int i = 0; i < 8; ++i)
#pragma unroll
        for (int j = 0; j < 4; ++j) acc[i][j] = 0;

#define STAGE(bs, kb)                                                           \
    do {                                                                        \
        ushort* bb = SH + (bs) * 16384;                                         \
        _Pragma("unroll") for (int k = 0; k < 4; ++k) {                         \
            const int u = tid + k * 512;                                        \
            const int r = (u & 1023) >> 2;                                      \
            const int sc = ((u & 3) ^ (r & 3) ^ ((r >> 2) & 3)) << 3;           \
            const ushort* src = (k < 2)                                         \
                ? &A[(size_t)(m0 + r) * K + (kb) + sc]                          \
                : &BT[(size_t)(n0 + r) * K + (kb) + sc];                        \
            gload16(src, bb + u * 8);                                           \
        }                                                                       \
    } while (0)

    const int nk = K >> 5;              // 32 K-tiles, BK = 32
    STAGE(0, 0);
    STAGE(1, 32);
    STAGE(2, 64);
    int bi = 0;
    for (int t = 0; t < nk; ++t) {
        // ---- K-tile boundary: certify buf[bi] staged for all threads ----
        if (t + 2 < nk) {
            asm volatile("s_waitcnt vmcnt(8)" ::: "memory");
        } else if (t + 1 < nk) {
            asm volatile("s_waitcnt vmcnt(4)" ::: "memory");
        } else {
            asm volatile("s_waitcnt vmcnt(0)" ::: "memory");
        }
        __builtin_amdgcn_s_barrier();
        __builtin_amdgcn_sched_barrier(0);
        const ushort* buf = SH + bi * 16384;

        // ---- phase 0: B all + A frags 0-3 (8 ds_read), stage t+3, 16 MFMA
        short8 a0[4], b[4];
#pragma unroll
        for (int nf = 0; nf < 4; ++nf)
            b[nf] = *(const short8*)&buf[8192 + (wc * 64 + nf * 16 + l15) * 32 + fcol];
#pragma unroll
        for (int mf = 0; mf < 4; ++mf)
            a0[mf] = *(const short8*)&buf[(wr * 128 + mf * 16 + l15) * 32 + fcol];
        if (t + 3 < nk) STAGE((bi + 3) & 3, (t + 3) << 5);
        __builtin_amdgcn_s_barrier();
        asm volatile("s_waitcnt lgkmcnt(0)" ::: "memory");
        __builtin_amdgcn_sched_barrier(0);
        __builtin_amdgcn_s_setprio(1);
#pragma unroll
        for (int mf = 0; mf < 4; ++mf)
#pragma unroll
            for (int nf = 0; nf < 4; ++nf)
                acc[mf][nf] = MFMA(a0[mf], b[nf], acc[mf][nf]);
        __builtin_amdgcn_s_setprio(0);
        __builtin_amdgcn_s_barrier();
        __builtin_amdgcn_sched_barrier(0);

        // ---- phase 1: A frags 4-7 (4 ds_read), 16 MFMA
        short8 a1[4];
#pragma unroll
        for (int mf = 0; mf < 4; ++mf)
            a1[mf] = *(const short8*)&buf[(wr * 128 + (mf + 4) * 16 + l15) * 32 + fcol];
        __builtin_amdgcn_s_barrier();
        asm volatile("s_waitcnt lgkmcnt(0)" ::: "memory");
        __builtin_amdgcn_sched_barrier(0);
        __builtin_amdgcn_s_setprio(1);
#pragma unroll
        for (int mf = 0; mf < 4; ++mf)
#pragma unroll
            for (int nf = 0; nf < 4; ++nf)
                acc[mf + 4][nf] = MFMA(a1[mf], b[nf], acc[mf + 4][nf]);
        __builtin_amdgcn_s_setprio(0);
        bi = (bi + 1) & 3;
        // phase-1 closing barrier == next iteration's boundary barrier
    }
#undef STAGE
    __syncthreads();                    // main-loop LDS dead before reuse

    const int sec = n0 >> 10;                       // 0=q, 1=k, 2=v (tiles align)
    if (sec < 2) {
        ushort* dstb = sec == 0 ? Qh : Kh;
        const float qs = sec == 0 ? 0.125f : 1.0f;
#pragma unroll
        for (int mf = 0; mf < 8; ++mf)
#pragma unroll
            for (int i = 0; i < 4; ++i) {
                const int row = m0 + wr * 128 + mf * 16 + lhi * 4 + i;
                const int b = row >> 10, s = row & 1023;
                int p = pos[s];
                p = p < 0 ? 0 : (p > MAXPOS - 1 ? MAXPOS - 1 : p);
#pragma unroll
                for (int nf = 0; nf < 4; ++nf) {
                    const int col = n0 + wc * 64 + nf * 16 + l15;
                    const int cw = col & 1023;
                    const int h = cw >> 6, d = cw & 63;
                    const float c  = tab[((size_t)p * 32 + (d >> 1)) * 2];
                    const float sn = tab[((size_t)p * 32 + (d >> 1)) * 2 + 1];
                    const float v = acc[mf][nf][i];
                    const float pr = __shfl_xor(v, 1);
                    const float o = (d & 1) ? (v * c + pr * sn) : (v * c - pr * sn);
                    dstb[((size_t)((b * 16 + h) * 1024 + s)) * 64 + d] = f2bf(o * qs);
                }
            }
    } else {
        // V: transpose via LDS bounce, two 128-row halves, T[128][264] pad
        ushort (*T)[264] = (ushort(*)[264]) & SH[0];
        const int bb = m0 >> 10;
        const int dd = tid & 255, sg = tid >> 8;     // dd: 4 heads x 64 dims
        const int hv = ((n0 & 1023) >> 6) + (dd >> 6);
        const int d = dd & 63;
#pragma unroll
        for (int h = 0; h < 2; ++h) {
            if (wr == h) {
#pragma unroll
                for (int mf = 0; mf < 8; ++mf)
#pragma unroll
                    for (int nf = 0; nf < 4; ++nf)
#pragma unroll
                        for (int i = 0; i < 4; ++i)
                            T[mf * 16 + lhi * 4 + i][wc * 64 + nf * 16 + l15] =
                                f2bf(acc[mf][nf][i]);
            }
            __syncthreads();
            const int s0 = (m0 & 1023) + h * 128;
            ushort* dst = Vt + ((size_t)(bb * 16 + hv) * 64 + d) * S_LEN + s0;
#pragma unroll
            for (int j = 0; j < 8; ++j) {
                const int ch = sg * 8 + j;           // 16 chunks of 8 seq
                __align__(16) ushort tmp[8];
#pragma unroll
                for (int e = 0; e < 8; ++e) tmp[e] = T[ch * 8 + e][dd];
                *(uint4*)&dst[ch * 8] = *(uint4*)tmp;
            }
            __syncthreads();
        }
    }
}

// ---------------- bf16 GEMM (128^2 ring) — out-projection -------------------
__global__ __launch_bounds__(256, 3) void k_gemm_out(
    const ushort* __restrict__ A, const ushort* __restrict__ BT,
    float* __restrict__ Cf, int M, int N, int K, int nbx) {
    __shared__ __align__(16) ushort SH[3 * 8192];   // 48 KB
    const int tid = threadIdx.x;
    const int lane = tid & 63, wave = tid >> 6;
    const int wr = wave >> 1, wc = wave & 1;
    const int l15 = lane & 15, lhi = lane >> 4;
    const int nby = gridDim.x / nbx;
    const int xcd = blockIdx.x & 7, idx = blockIdx.x >> 3;
    const int Creg = nbx >> 1, Rreg = nby >> 2;
    const int by = (xcd >> 1) * Rreg + idx / Creg;
    const int bx = (xcd & 1) * Creg + idx % Creg;
    const int m0 = by << 7, n0 = bx << 7;

    const int srow = tid >> 2;                                        // 0..63
    const int scol = (((tid >> 2) & 3) ^ ((tid >> 4) & 3) ^ (tid & 3)) << 3;
    const int fcol = ((lhi ^ ((l15 & 3) ^ ((l15 >> 2) & 3)))) << 3;

    f32x4 acc[4][4];
#pragma unroll
    for (int i = 0; i < 4; ++i)
#pragma unroll
        for (int j = 0; j < 4; ++j) acc[i][j] = 0;

#define STAGE(bs, kb)                                                           \
    do {                                                                        \
        ushort* bb = SH + (bs) * 8192;                                          \
        gload16(&A[(size_t)(m0 + srow) * K + (kb) + scol], bb + tid * 8);       \
        gload16(&A[(size_t)(m0 + 64 + srow) * K + (kb) + scol],                 \
                bb + 2048 + tid * 8);                                           \
        gload16(&BT[(size_t)(n0 + srow) * K + (kb) + scol],                     \
                bb + 4096 + tid * 8);                                           \
        gload16(&BT[(size_t)(n0 + 64 + srow) * K + (kb) + scol],                \
                bb + 6144 + tid * 8);                                           \
    } while (0)

    const int nk = K >> 5;              // BK = 32
    STAGE(0, 0);
    STAGE(1, 32);
    int bi = 0;
    for (int t = 0; t < nk; ++t) {
        if (t + 1 < nk) {
            asm volatile("s_waitcnt vmcnt(4)" ::: "memory");
        } else {
            asm volatile("s_waitcnt vmcnt(0)" ::: "memory");
        }
        __builtin_amdgcn_s_barrier();
        __builtin_amdgcn_sched_barrier(0);
        if (t + 2 < nk) {
            int bs = bi + 2;
            if (bs >= 3) bs -= 3;
            STAGE(bs, (t + 2) << 5);
        }
        const ushort* bufA = SH + bi * 8192;
        const ushort* bufB = bufA + 4096;
        short8 a[4], b[4];
#pragma unroll
        for (int fm = 0; fm < 4; ++fm)
            a[fm] = *(const short8*)&bufA[(wr * 64 + fm * 16 + l15) * 32 + fcol];
#pragma unroll
        for (int fn = 0; fn < 4; ++fn)
            b[fn] = *(const short8*)&bufB[(wc * 64 + fn * 16 + l15) * 32 + fcol];
#pragma unroll
        for (int fm = 0; fm < 4; ++fm)
#pragma unroll
            for (int fn = 0; fn < 4; ++fn)
                acc[fm][fn] = MFMA(a[fm], b[fn], acc[fm][fn]);
        bi = (bi == 2) ? 0 : bi + 1;
    }
#undef STAGE

#pragma unroll
    for (int fm = 0; fm < 4; ++fm)
#pragma unroll
        for (int fn = 0; fn < 4; ++fn)
#pragma unroll
            for (int i = 0; i < 4; ++i) {
                int row = m0 + wr * 64 + fm * 16 + lhi * 4 + i;
                int col = n0 + wc * 64 + fn * 16 + l15;
                Cf[(size_t)row * N + col] = acc[fm][fn][i];
            }
}

// ---------------- flash attention, dual q-tile per block --------------------
__global__ __launch_bounds__(256, 3) void k_attn(const ushort* __restrict__ Qh,
                                                 const ushort* __restrict__ Kh,
                                                 const ushort* __restrict__ Vt,
                                                 ushort* __restrict__ attnB) {
    __shared__ __align__(16) ushort Ks[2][64][64];   // 16 KB
    __shared__ __align__(16) ushort Vs[2][64][64];   // 16 KB
    __shared__ __align__(16) ushort P[4][16][72];    // 9 KB
    const int bh = blockIdx.x;
    const int g  = blockIdx.y;                       // 0..7
    const int gA = g, gB = 15 - g;
    const int nkb = gB + 1;                          // 9..16 loop iters
    const int tid = threadIdx.x;
    const int wave = tid >> 6, lane = tid & 63;
    const int l15 = lane & 15, lhi = lane >> 4;
    const int b = bh >> 4, h = bh & 15;
    const ushort* Qp = Qh + (size_t)bh * S_LEN * 64;
    const ushort* Kp = Kh + (size_t)bh * S_LEN * 64;
    const ushort* Vp = Vt + (size_t)bh * 64 * S_LEN;
    const int qbA = (gA << 6) + (wave << 4);
    const int qbB = (gB << 6) + (wave << 4);
    const int qrowbA = qbA + lhi * 4;
    const int qrowbB = qbB + lhi * 4;

    const int U0 = tid, U1 = tid + 256;
    const int r0 = U0 >> 3, o0 = ((U0 & 7) ^ (r0 & 7)) << 3;   // ushort offset
    const int r1 = U1 >> 3, o1 = ((U1 & 7) ^ (r1 & 7)) << 3;
    ushort* KsF = &Ks[0][0][0];
    ushort* VsF = &Vs[0][0][0];

    short8 aQA0 = *(const short8*)&Qp[(size_t)(qbA + l15) * 64 + lhi * 8];
    short8 aQA1 = *(const short8*)&Qp[(size_t)(qbA + l15) * 64 + 32 + lhi * 8];
    short8 aQB0 = *(const short8*)&Qp[(size_t)(qbB + l15) * 64 + lhi * 8];
    short8 aQB1 = *(const short8*)&Qp[(size_t)(qbB + l15) * 64 + 32 + lhi * 8];

    short8 ones;
#pragma unroll
    for (int j = 0; j < 8; ++j) ones[j] = (short)0x3F80;   // bf16 1.0

    f32x4 OA0{}, OA1{}, OA2{}, OA3{}, ssumA{};
    f32x4 OB0{}, OB1{}, OB2{}, OB3{}, ssumB{};

    gload16(&Kp[(size_t)r0 * 64 + o0], KsF + U0 * 8);
    gload16(&Kp[(size_t)r1 * 64 + o1], KsF + U1 * 8);
    gload16(&Vp[(size_t)r0 * S_LEN + o0], VsF + U0 * 8);
    gload16(&Vp[(size_t)r1 * S_LEN + o1], VsF + U1 * 8);
    __syncthreads();

#define LDSK(s, kk) (*(const short8*)(KsF + (cur << 12) + ((((s) << 4) + l15) << 6) + \
                                      ((((kk) * 4 + lhi) ^ (l15 & 7)) << 3)))
#define LDSV(n, kk) (*(const short8*)(VsF + (cur << 12) + ((((n) << 4) + l15) << 6) + \
                                      ((((kk) * 4 + lhi) ^ (l15 & 7)) << 3)))
#define EXPST(SV, SUB)                                                         \
    _Pragma("unroll") for (int i = 0; i < 4; ++i) {                            \
        P[wave][lhi * 4 + i][(SUB) * 16 + l15] = f2bf(__expf(SV[i] - 8.f));    \
    }
#define EXPSTM(SV, SUB, QROWB)                                                 \
    _Pragma("unroll") for (int i = 0; i < 4; ++i) {                            \
        float v = SV[i];                                                       \
        if (k0 + (SUB) * 16 + l15 > (QROWB) + i) v = -1e30f;                   \
        P[wave][lhi * 4 + i][(SUB) * 16 + l15] = f2bf(__expf(v - 8.f));        \
    }

    int cur = 0;
    for (int kb = 0; kb < nkb; ++kb) {
        const int k0 = kb << 6;
        if (kb + 1 < nkb) {
            const int kn = k0 + 64;
            const int bo = (cur ^ 1) << 12;
            gload16(&Kp[(size_t)(kn + r0) * 64 + o0], KsF + bo + U0 * 8);
            gload16(&Kp[(size_t)(kn + r1) * 64 + o1], KsF + bo + U1 * 8);
            gload16(&Vp[(size_t)r0 * S_LEN + kn + o0], VsF + bo + U0 * 8);
            gload16(&Vp[(size_t)r1 * S_LEN + kn + o1], VsF + bo + U1 * 8);
        }

        if (kb <= gA) {                    // ---- tile A (block-uniform cond)
            __builtin_amdgcn_s_setprio(1);
            f32x4 s0{}, s1{}, s2{}, s3{};
            s0 = MFMA(aQA0, LDSK(0, 0), s0); s0 = MFMA(aQA1, LDSK(0, 1), s0);
            s1 = MFMA(aQA0, LDSK(1, 0), s1); s1 = MFMA(aQA1, LDSK(1, 1), s1);
            s2 = MFMA(aQA0, LDSK(2, 0), s2); s2 = MFMA(aQA1, LDSK(2, 1), s2);
            s3 = MFMA(aQA0, LDSK(3, 0), s3); s3 = MFMA(aQA1, LDSK(3, 1), s3);
            __builtin_amdgcn_s_setprio(0);
            if (kb == gA) {
                EXPSTM(s0, 0, qrowbA) EXPSTM(s1, 1, qrowbA)
                EXPSTM(s2, 2, qrowbA) EXPSTM(s3, 3, qrowbA)
            } else {
                EXPST(s0, 0) EXPST(s1, 1) EXPST(s2, 2) EXPST(s3, 3)
            }
            short8 aP0 = *(const short8*)&P[wave][l15][lhi * 8];
            short8 aP1 = *(const short8*)&P[wave][l15][32 + lhi * 8];
            __builtin_amdgcn_s_setprio(1);
            ssumA = MFMA(aP0, ones, ssumA); ssumA = MFMA(aP1, ones, ssumA);
            OA0 = MFMA(aP0, LDSV(0, 0), OA0); OA0 = MFMA(aP1, LDSV(0, 1), OA0);
            OA1 = MFMA(aP0, LDSV(1, 0), OA1); OA1 = MFMA(aP1, LDSV(1, 1), OA1);
            OA2 = MFMA(aP0, LDSV(2, 0), OA2); OA2 = MFMA(aP1, LDSV(2, 1), OA2);
            OA3 = MFMA(aP0, LDSV(3, 0), OA3); OA3 = MFMA(aP1, LDSV(3, 1), OA3);
            __builtin_amdgcn_s_setprio(0);
        }

        {                                   // ---- tile B (always active)
            __builtin_amdgcn_s_setprio(1);
            f32x4 s0{}, s1{}, s2{}, s3{};
            s0 = MFMA(aQB0, LDSK(0, 0), s0); s0 = MFMA(aQB1, LDSK(0, 1), s0);
            s1 = MFMA(aQB0, LDSK(1, 0), s1); s1 = MFMA(aQB1, LDSK(1, 1), s1);
            s2 = MFMA(aQB0, LDSK(2, 0), s2); s2 = MFMA(aQB1, LDSK(2, 1), s2);
            s3 = MFMA(aQB0, LDSK(3, 0), s3); s3 = MFMA(aQB1, LDSK(3, 1), s3);
            __builtin_amdgcn_s_setprio(0);
            if (kb == gB) {
                EXPSTM(s0, 0, qrowbB) EXPSTM(s1, 1, qrowbB)
                EXPSTM(s2, 2, qrowbB) EXPSTM(s3, 3, qrowbB)
            } else {
                EXPST(s0, 0) EXPST(s1, 1) EXPST(s2, 2) EXPST(s3, 3)
            }
            short8 aP0 = *(const short8*)&P[wave][l15][lhi * 8];
            short8 aP1 = *(const short8*)&P[wave][l15][32 + lhi * 8];
            __builtin_amdgcn_s_setprio(1);
            ssumB = MFMA(aP0, ones, ssumB); ssumB = MFMA(aP1, ones, ssumB);
            OB0 = MFMA(aP0, LDSV(0, 0), OB0); OB0 = MFMA(aP1, LDSV(0, 1), OB0);
            OB1 = MFMA(aP0, LDSV(1, 0), OB1); OB1 = MFMA(aP1, LDSV(1, 1), OB1);
            OB2 = MFMA(aP0, LDSV(2, 0), OB2); OB2 = MFMA(aP1, LDSV(2, 1), OB2);
            OB3 = MFMA(aP0, LDSV(3, 0), OB3); OB3 = MFMA(aP1, LDSV(3, 1), OB3);
            __builtin_amdgcn_s_setprio(0);
        }

        __syncthreads();
        cur ^= 1;
    }
#undef LDSK
#undef LDSV
#undef EXPST
#undef EXPSTM

#define WOUT(OV, N, QB, INV)                                                   \
    _Pragma("unroll") for (int i = 0; i < 4; ++i) {                            \
        int row = (QB) + lhi * 4 + i;                                          \
        attnB[((size_t)(b * S_LEN + row)) * DM + h * 64 + (N) * 16 + l15] =    \
            f2bf(OV[i] * INV[i]);                                              \
    }
    {
        f32x4 invA, invB;
#pragma unroll
        for (int i = 0; i < 4; ++i) {
            invA[i] = 1.f / ssumA[i];
            invB[i] = 1.f / ssumB[i];
        }
        WOUT(OA0, 0, qbA, invA) WOUT(OA1, 1, qbA, invA)
        WOUT(OA2, 2, qbA, invA) WOUT(OA3, 3, qbA, invA)
        WOUT(OB0, 0, qbB, invB) WOUT(OB1, 1, qbB, invB)
        WOUT(OB2, 2, qbB, invB) WOUT(OB3, 3, qbB, invB)
    }
#undef WOUT
}

// ---------------------------------------------------------------------------
extern "C" void kernel_launch(void* const* d_in, const int* in_sizes, int n_in,
                              void* d_out, int out_size, void* d_ws, size_t ws_size,
                              hipStream_t stream) {
    (void)in_sizes; (void)n_in; (void)out_size; (void)ws_size;
    const float* hs   = (const float*)d_in[0];
    const int*   pos  = (const int*)d_in[1];
    const float* Wqkv = (const float*)d_in[3];
    const float* Wout = (const float*)d_in[4];
    float* out = (float*)d_out;

    char* ws = (char*)d_ws;
    size_t off = 0;
    ushort* hsB   = (ushort*)(ws + off); off += (size_t)4096 * 1024 * 2;   // 8MB
    ushort* WqkvB = (ushort*)(ws + off); off += (size_t)3072 * 1024 * 2;   // 6MB
    ushort* WoutB = (ushort*)(ws + off); off += (size_t)1024 * 1024 * 2;   // 2MB
    ushort* Qh    = (ushort*)(ws + off); off += (size_t)NBH * 1024 * 64 * 2; // 8MB
    ushort* Kh    = (ushort*)(ws + off); off += (size_t)NBH * 1024 * 64 * 2; // 8MB
    ushort* Vt    = (ushort*)(ws + off); off += (size_t)NBH * 64 * 1024 * 2; // 8MB
    ushort* attnB = (ushort*)(ws + off); off += (size_t)4096 * 1024 * 2;   // 8MB
    float*  tab   = (float*)(ws + off);  off += (size_t)4096 * 32 * 2 * 4; // 1MB

    // conversions + RoPE table, one launch (8704 = 8192 cvt + 512 tab blocks)
    k_cvt3<<<8704, 256, 0, stream>>>((const float4*)hs, (const float4*)Wqkv,
                                     (const float4*)Wout, (ushort4*)hsB,
                                     (ushort4*)WqkvB, (ushort4*)WoutB, tab);

    // GEMM1 fused: qkv proj + RoPE + head split + V transpose (256^2, 8-wave,
    // double-barrier phase schedule)
    k_gemm256<<<192, 512, 0, stream>>>(hsB, WqkvB, pos, tab, Qh, Kh, Vt);

    // attention: dual q-tile blocks, grid (bh, g)
    k_attn<<<dim3(64, 8), 256, 0, stream>>>(Qh, Kh, Vt, attnB);

    // GEMM2: out projection, f32 output (128^2 ring)
    k_gemm_out<<<256, 256, 0, stream>>>(attnB, WoutB, out, 4096, 1024, 1024, 8);
}

// Round 14
// 93.394 us; speedup vs baseline: 1.0598x; 1.0598x over previous
//
#include <hip/hip_runtime.h>

typedef __attribute__((ext_vector_type(8))) short short8;
typedef __attribute__((ext_vector_type(4))) float f32x4;

#define MFMA(a, b, c) __builtin_amdgcn_mfma_f32_16x16x32_bf16((a), (b), (c), 0, 0, 0)

#define S_LEN 1024
#define DM 1024
#define NHEADS 16
#define HD 64
#define NBH 64          // B * NHEADS = 4 * 16
#define MAXPOS 4096

__device__ __forceinline__ ushort f2bf(float f) {
    unsigned u = __builtin_bit_cast(unsigned, f);
    u += 0x7fffu + ((u >> 16) & 1u);
    return (ushort)(u >> 16);
}
__device__ __forceinline__ float bf2f(ushort h) {
    return __builtin_bit_cast(float, (unsigned)h << 16);
}

// async global->LDS, 16B per lane. LDS dest must be base + lane*16 linear.
__device__ __forceinline__ void gload16(const ushort* g, ushort* l) {
    __builtin_amdgcn_global_load_lds(
        (const __attribute__((address_space(1))) unsigned int*)g,
        (__attribute__((address_space(3))) unsigned int*)l, 16, 0, 0);
}

// ------- fp32 -> bf16 conversion (3 tensors) + RoPE table, one launch -------
__global__ __launch_bounds__(256) void k_cvt3(const float4* __restrict__ hs,
                                              const float4* __restrict__ wqkv,
                                              const float4* __restrict__ wout,
                                              ushort4* __restrict__ hsB,
                                              ushort4* __restrict__ wqkvB,
                                              ushort4* __restrict__ woutB,
                                              float* __restrict__ tab) {
    int id = blockIdx.x * 256 + threadIdx.x;
    if (id < 2097152) {
        const float4* src;
        ushort4* dst;
        int off;
        if (id < 1048576)      { src = hs;   dst = hsB;   off = id; }
        else if (id < 1835008) { src = wqkv; dst = wqkvB; off = id - 1048576; }
        else                   { src = wout; dst = woutB; off = id - 1835008; }
        float4 v = src[off];
        ushort4 o;
        o.x = f2bf(v.x); o.y = f2bf(v.y); o.z = f2bf(v.z); o.w = f2bf(v.w);
        dst[off] = o;
    } else {
        int t = id - 2097152;             // 0..131071 = 4096 pos x 32 freq
        int p = t >> 5, i = t & 31;
        float inv = powf(10000.f, -(float)(2 * i) / 64.f);
        float th = (float)p * inv;
        float s, c;
        sincosf(th, &s, &c);
        tab[2 * t] = c;
        tab[2 * t + 1] = s;
    }
}

// ---------------- bf16 GEMM, C = A @ B^T, 128x128 tile, 8 waves -------------
// Counted-vmcnt ring (R7/R12-proven sync): BK=32, 3 LDS bufs, stage 2 K-tiles
// ahead, vmcnt(2/0) ladder (2 loads/thread/STAGE at 512 thr), raw s_barrier,
// compiler-scheduled ds_read/MFMA interleave, T2 chunk-XOR swizzle.
// SINGLE-VARIABLE CHANGE vs R12: 256->512 threads (wave grid 2x4, wave tile
// 64x32, acc[4][2]) -> 6 waves/SIMD at 3 blocks/CU for latency hiding.
// MODE 0: f32 C. MODE 1: fused RoPE/head-split/V-transpose epilogue (R6's
// verified 8-wave epilogue code).
template <int MODE>
__global__ __launch_bounds__(512, 6) void k_gemm(
    const ushort* __restrict__ A, const ushort* __restrict__ BT,
    float* __restrict__ Cf,
    const int* __restrict__ pos, const float* __restrict__ tab,
    ushort* __restrict__ Qh, ushort* __restrict__ Kh, ushort* __restrict__ Vt,
    int M, int N, int K, int nbx) {
    __shared__ __align__(16) ushort SH[3 * 8192];   // 48 KB
    const int tid = threadIdx.x;                 // 0..511
    const int lane = tid & 63, wave = tid >> 6;  // 8 waves
    const int wr = wave >> 2, wc = wave & 3;     // 2 x 4
    const int l15 = lane & 15, lhi = lane >> 4;
    const int nby = gridDim.x / nbx;
    const int xcd = blockIdx.x & 7, idx = blockIdx.x >> 3;
    const int Creg = nbx >> 1, Rreg = nby >> 2;
    const int by = (xcd >> 1) * Rreg + idx / Creg;
    const int bx = (xcd & 1) * Creg + idx % Creg;
    const int m0 = by << 7, n0 = bx << 7;

    // staging: A = 512 chunks (row tid>>2, chunk tid&3), B likewise; source
    // chunk pre-swizzled by (r&3)^((r>>2)&3); dest linear (wave-contiguous).
    const int srow = tid >> 2;                                        // 0..127
    const int scol = (((tid & 3) ^ (srow & 3) ^ ((srow >> 2) & 3)) << 3);
    // read-side: row base multiple of 16 + l15 -> chunk lhi ^ (l15&3)^((l15>>2)&3)
    const int fcol = ((lhi ^ ((l15 & 3) ^ ((l15 >> 2) & 3)))) << 3;

    f32x4 acc[4][2];
#pragma unroll
    for (int i = 0; i < 4; ++i)
#pragma unroll
        for (int j = 0; j < 2; ++j) acc[i][j] = 0;

#define STAGE(bs, kb)                                                           \
    do {                                                                        \
        ushort* bb = SH + (bs) * 8192;                                          \
        gload16(&A[(size_t)(m0 + srow) * K + (kb) + scol], bb + tid * 8);       \
        gload16(&BT[(size_t)(n0 + srow) * K + (kb) + scol],                     \
                bb + 4096 + tid * 8);                                           \
    } while (0)

    const int nk = K >> 5;              // BK = 32
    STAGE(0, 0);
    STAGE(1, 32);
    int bi = 0;
    for (int t = 0; t < nk; ++t) {
        if (t + 1 < nk) {
            asm volatile("s_waitcnt vmcnt(2)" ::: "memory");
        } else {
            asm volatile("s_waitcnt vmcnt(0)" ::: "memory");
        }
        __builtin_amdgcn_s_barrier();
        __builtin_amdgcn_sched_barrier(0);   // pin: nothing crosses the publish point
        if (t + 2 < nk) {
            int bs = bi + 2;
            if (bs >= 3) bs -= 3;
            STAGE(bs, (t + 2) << 5);
        }
        const ushort* bufA = SH + bi * 8192;
        const ushort* bufB = bufA + 4096;
        short8 a[4], b[2];
#pragma unroll
        for (int fm = 0; fm < 4; ++fm)
            a[fm] = *(const short8*)&bufA[(wr * 64 + fm * 16 + l15) * 32 + fcol];
#pragma unroll
        for (int fn = 0; fn < 2; ++fn)
            b[fn] = *(const short8*)&bufB[(wc * 32 + fn * 16 + l15) * 32 + fcol];
#pragma unroll
        for (int fm = 0; fm < 4; ++fm)
#pragma unroll
            for (int fn = 0; fn < 2; ++fn)
                acc[fm][fn] = MFMA(a[fm], b[fn], acc[fm][fn]);
        bi = (bi == 2) ? 0 : bi + 1;
    }
#undef STAGE
    __syncthreads();                    // LDS reuse (V-transpose bounce) safety

    if (MODE == 0) {
#pragma unroll
        for (int fm = 0; fm < 4; ++fm)
#pragma unroll
            for (int fn = 0; fn < 2; ++fn)
#pragma unroll
                for (int i = 0; i < 4; ++i) {
                    int row = m0 + wr * 64 + fm * 16 + lhi * 4 + i;
                    int col = n0 + wc * 32 + fn * 16 + l15;
                    Cf[(size_t)row * N + col] = acc[fm][fn][i];
                }
    } else {
        const int sec = n0 >> 10;                       // 0=q, 1=k, 2=v
        if (sec < 2) {
            ushort* dstb = sec == 0 ? Qh : Kh;
            const float qs = sec == 0 ? 0.125f : 1.0f;
#pragma unroll
            for (int fm = 0; fm < 4; ++fm)
#pragma unroll
                for (int i = 0; i < 4; ++i) {
                    const int row = m0 + wr * 64 + fm * 16 + lhi * 4 + i;
                    const int b = row >> 10, s = row & 1023;
                    int p = pos[s];
                    p = p < 0 ? 0 : (p > MAXPOS - 1 ? MAXPOS - 1 : p);
#pragma unroll
                    for (int fn = 0; fn < 2; ++fn) {
                        const int col = n0 + wc * 32 + fn * 16 + l15;
                        const int cw = col & 1023;
                        const int h = cw >> 6, d = cw & 63;
                        const float c  = tab[((size_t)p * 32 + (d >> 1)) * 2];
                        const float sn = tab[((size_t)p * 32 + (d >> 1)) * 2 + 1];
                        const float v = acc[fm][fn][i];
                        const float pr = __shfl_xor(v, 1);
                        const float o = (d & 1) ? (v * c + pr * sn) : (v * c - pr * sn);
                        dstb[((size_t)((b * 16 + h) * 1024 + s)) * 64 + d] = f2bf(o * qs);
                    }
                }
        } else {
            // V: transpose via LDS bounce (reuse staging buffer), [128][132] pad
            ushort (*T)[132] = (ushort(*)[132]) & SH[0];
#pragma unroll
            for (int fm = 0; fm < 4; ++fm)
#pragma unroll
                for (int fn = 0; fn < 2; ++fn)
#pragma unroll
                    for (int i = 0; i < 4; ++i)
                        T[wr * 64 + fm * 16 + lhi * 4 + i][wc * 32 + fn * 16 + l15] =
                            f2bf(acc[fm][fn][i]);
            __syncthreads();
            const int b = m0 >> 10, s0 = m0 & 1023;
            const int dd = tid & 127, grp = tid >> 7;   // dd: 2 heads x 64 dims
            const int hv = ((n0 & 1023) >> 6) + (dd >> 6);
            const int d = dd & 63;
            ushort* dst = Vt + ((size_t)(b * 16 + hv) * 64 + d) * S_LEN + s0;
#pragma unroll
            for (int j = 0; j < 4; ++j) {
                const int ch = grp * 4 + j;             // 16 chunks of 8 seq
                __align__(16) ushort tmp[8];
#pragma unroll
                for (int e = 0; e < 8; ++e) tmp[e] = T[ch * 8 + e][dd];
                *(uint4*)&dst[ch * 8] = *(uint4*)tmp;
            }
        }
    }
}

// ---------------- flash attention, dual q-tile per block (R12-exact) --------
__global__ __launch_bounds__(256, 3) void k_attn(const ushort* __restrict__ Qh,
                                                 const ushort* __restrict__ Kh,
                                                 const ushort* __restrict__ Vt,
                                                 ushort* __restrict__ attnB) {
    __shared__ __align__(16) ushort Ks[2][64][64];   // 16 KB
    __shared__ __align__(16) ushort Vs[2][64][64];   // 16 KB
    __shared__ __align__(16) ushort P[4][16][72];    // 9 KB
    const int bh = blockIdx.x;
    const int g  = blockIdx.y;                       // 0..7
    const int gA = g, gB = 15 - g;
    const int nkb = gB + 1;                          // 9..16 loop iters
    const int tid = threadIdx.x;
    const int wave = tid >> 6, lane = tid & 63;
    const int l15 = lane & 15, lhi = lane >> 4;
    const int b = bh >> 4, h = bh & 15;
    const ushort* Qp = Qh + (size_t)bh * S_LEN * 64;
    const ushort* Kp = Kh + (size_t)bh * S_LEN * 64;
    const ushort* Vp = Vt + (size_t)bh * 64 * S_LEN;
    const int qbA = (gA << 6) + (wave << 4);
    const int qbB = (gB << 6) + (wave << 4);
    const int qrowbA = qbA + lhi * 4;
    const int qrowbB = qbB + lhi * 4;

    const int U0 = tid, U1 = tid + 256;
    const int r0 = U0 >> 3, o0 = ((U0 & 7) ^ (r0 & 7)) << 3;   // ushort offset
    const int r1 = U1 >> 3, o1 = ((U1 & 7) ^ (r1 & 7)) << 3;
    ushort* KsF = &Ks[0][0][0];
    ushort* VsF = &Vs[0][0][0];

    short8 aQA0 = *(const short8*)&Qp[(size_t)(qbA + l15) * 64 + lhi * 8];
    short8 aQA1 = *(const short8*)&Qp[(size_t)(qbA + l15) * 64 + 32 + lhi * 8];
    short8 aQB0 = *(const short8*)&Qp[(size_t)(qbB + l15) * 64 + lhi * 8];
    short8 aQB1 = *(const short8*)&Qp[(size_t)(qbB + l15) * 64 + 32 + lhi * 8];

    short8 ones;
#pragma unroll
    for (int j = 0; j < 8; ++j) ones[j] = (short)0x3F80;   // bf16 1.0

    f32x4 OA0{}, OA1{}, OA2{}, OA3{}, ssumA{};
    f32x4 OB0{}, OB1{}, OB2{}, OB3{}, ssumB{};

    gload16(&Kp[(size_t)r0 * 64 + o0], KsF + U0 * 8);
    gload16(&Kp[(size_t)r1 * 64 + o1], KsF + U1 * 8);
    gload16(&Vp[(size_t)r0 * S_LEN + o0], VsF + U0 * 8);
    gload16(&Vp[(size_t)r1 * S_LEN + o1], VsF + U1 * 8);
    __syncthreads();

#define LDSK(s, kk) (*(const short8*)(KsF + (cur << 12) + ((((s) << 4) + l15) << 6) + \
                                      ((((kk) * 4 + lhi) ^ (l15 & 7)) << 3)))
#define LDSV(n, kk) (*(const short8*)(VsF + (cur << 12) + ((((n) << 4) + l15) << 6) + \
                                      ((((kk) * 4 + lhi) ^ (l15 & 7)) << 3)))
#define EXPST(SV, SUB)                                                         \
    _Pragma("unroll") for (int i = 0; i < 4; ++i) {                            \
        P[wave][lhi * 4 + i][(SUB) * 16 + l15] = f2bf(__expf(SV[i] - 8.f));    \
    }
#define EXPSTM(SV, SUB, QROWB)                                                 \
    _Pragma("unroll") for (int i = 0; i < 4; ++i) {                            \
        float v = SV[i];                                                       \
        if (k0 + (SUB) * 16 + l15 > (QROWB) + i) v = -1e30f;                   \
        P[wave][lhi * 4 + i][(SUB) * 16 + l15] = f2bf(__expf(v - 8.f));        \
    }

    int cur = 0;
    for (int kb = 0; kb < nkb; ++kb) {
        const int k0 = kb << 6;
        if (kb + 1 < nkb) {
            const int kn = k0 + 64;
            const int bo = (cur ^ 1) << 12;
            gload16(&Kp[(size_t)(kn + r0) * 64 + o0], KsF + bo + U0 * 8);
            gload16(&Kp[(size_t)(kn + r1) * 64 + o1], KsF + bo + U1 * 8);
            gload16(&Vp[(size_t)r0 * S_LEN + kn + o0], VsF + bo + U0 * 8);
            gload16(&Vp[(size_t)r1 * S_LEN + kn + o1], VsF + bo + U1 * 8);
        }

        if (kb <= gA) {                    // ---- tile A (block-uniform cond)
            __builtin_amdgcn_s_setprio(1);
            f32x4 s0{}, s1{}, s2{}, s3{};
            s0 = MFMA(aQA0, LDSK(0, 0), s0); s0 = MFMA(aQA1, LDSK(0, 1), s0);
            s1 = MFMA(aQA0, LDSK(1, 0), s1); s1 = MFMA(aQA1, LDSK(1, 1), s1);
            s2 = MFMA(aQA0, LDSK(2, 0), s2); s2 = MFMA(aQA1, LDSK(2, 1), s2);
            s3 = MFMA(aQA0, LDSK(3, 0), s3); s3 = MFMA(aQA1, LDSK(3, 1), s3);
            __builtin_amdgcn_s_setprio(0);
            if (kb == gA) {
                EXPSTM(s0, 0, qrowbA) EXPSTM(s1, 1, qrowbA)
                EXPSTM(s2, 2, qrowbA) EXPSTM(s3, 3, qrowbA)
            } else {
                EXPST(s0, 0) EXPST(s1, 1) EXPST(s2, 2) EXPST(s3, 3)
            }
            short8 aP0 = *(const short8*)&P[wave][l15][lhi * 8];
            short8 aP1 = *(const short8*)&P[wave][l15][32 + lhi * 8];
            __builtin_amdgcn_s_setprio(1);
            ssumA = MFMA(aP0, ones, ssumA); ssumA = MFMA(aP1, ones, ssumA);
            OA0 = MFMA(aP0, LDSV(0, 0), OA0); OA0 = MFMA(aP1, LDSV(0, 1), OA0);
            OA1 = MFMA(aP0, LDSV(1, 0), OA1); OA1 = MFMA(aP1, LDSV(1, 1), OA1);
            OA2 = MFMA(aP0, LDSV(2, 0), OA2); OA2 = MFMA(aP1, LDSV(2, 1), OA2);
            OA3 = MFMA(aP0, LDSV(3, 0), OA3); OA3 = MFMA(aP1, LDSV(3, 1), OA3);
            __builtin_amdgcn_s_setprio(0);
        }

        {                                   // ---- tile B (always active)
            __builtin_amdgcn_s_setprio(1);
            f32x4 s0{}, s1{}, s2{}, s3{};
            s0 = MFMA(aQB0, LDSK(0, 0), s0); s0 = MFMA(aQB1, LDSK(0, 1), s0);
            s1 = MFMA(aQB0, LDSK(1, 0), s1); s1 = MFMA(aQB1, LDSK(1, 1), s1);
            s2 = MFMA(aQB0, LDSK(2, 0), s2); s2 = MFMA(aQB1, LDSK(2, 1), s2);
            s3 = MFMA(aQB0, LDSK(3, 0), s3); s3 = MFMA(aQB1, LDSK(3, 1), s3);
            __builtin_amdgcn_s_setprio(0);
            if (kb == gB) {
                EXPSTM(s0, 0, qrowbB) EXPSTM(s1, 1, qrowbB)
                EXPSTM(s2, 2, qrowbB) EXPSTM(s3, 3, qrowbB)
            } else {
                EXPST(s0, 0) EXPST(s1, 1) EXPST(s2, 2) EXPST(s3, 3)
            }
            short8 aP0 = *(const short8*)&P[wave][l15][lhi * 8];
            short8 aP1 = *(const short8*)&P[wave][l15][32 + lhi * 8];
            __builtin_amdgcn_s_setprio(1);
            ssumB = MFMA(aP0, ones, ssumB); ssumB = MFMA(aP1, ones, ssumB);
            OB0 = MFMA(aP0, LDSV(0, 0), OB0); OB0 = MFMA(aP1, LDSV(0, 1), OB0);
            OB1 = MFMA(aP0, LDSV(1, 0), OB1); OB1 = MFMA(aP1, LDSV(1, 1), OB1);
            OB2 = MFMA(aP0, LDSV(2, 0), OB2); OB2 = MFMA(aP1, LDSV(2, 1), OB2);
            OB3 = MFMA(aP0, LDSV(3, 0), OB3); OB3 = MFMA(aP1, LDSV(3, 1), OB3);
            __builtin_amdgcn_s_setprio(0);
        }

        __syncthreads();
        cur ^= 1;
    }
#undef LDSK
#undef LDSV
#undef EXPST
#undef EXPSTM

#define WOUT(OV, N, QB, INV)                                                   \
    _Pragma("unroll") for (int i = 0; i < 4; ++i) {                            \
        int row = (QB) + lhi * 4 + i;                                          \
        attnB[((size_t)(b * S_LEN + row)) * DM + h * 64 + (N) * 16 + l15] =    \
            f2bf(OV[i] * INV[i]);                                              \
    }
    {
        f32x4 invA, invB;
#pragma unroll
        for (int i = 0; i < 4; ++i) {
            invA[i] = 1.f / ssumA[i];
            invB[i] = 1.f / ssumB[i];
        }
        WOUT(OA0, 0, qbA, invA) WOUT(OA1, 1, qbA, invA)
        WOUT(OA2, 2, qbA, invA) WOUT(OA3, 3, qbA, invA)
        WOUT(OB0, 0, qbB, invB) WOUT(OB1, 1, qbB, invB)
        WOUT(OB2, 2, qbB, invB) WOUT(OB3, 3, qbB, invB)
    }
#undef WOUT
}

// ---------------------------------------------------------------------------
extern "C" void kernel_launch(void* const* d_in, const int* in_sizes, int n_in,
                              void* d_out, int out_size, void* d_ws, size_t ws_size,
                              hipStream_t stream) {
    (void)in_sizes; (void)n_in; (void)out_size; (void)ws_size;
    const float* hs   = (const float*)d_in[0];
    const int*   pos  = (const int*)d_in[1];
    const float* Wqkv = (const float*)d_in[3];
    const float* Wout = (const float*)d_in[4];
    float* out = (float*)d_out;

    char* ws = (char*)d_ws;
    size_t off = 0;
    ushort* hsB   = (ushort*)(ws + off); off += (size_t)4096 * 1024 * 2;   // 8MB
    ushort* WqkvB = (ushort*)(ws + off); off += (size_t)3072 * 1024 * 2;   // 6MB
    ushort* WoutB = (ushort*)(ws + off); off += (size_t)1024 * 1024 * 2;   // 2MB
    ushort* Qh    = (ushort*)(ws + off); off += (size_t)NBH * 1024 * 64 * 2; // 8MB
    ushort* Kh    = (ushort*)(ws + off); off += (size_t)NBH * 1024 * 64 * 2; // 8MB
    ushort* Vt    = (ushort*)(ws + off); off += (size_t)NBH * 64 * 1024 * 2; // 8MB
    ushort* attnB = (ushort*)(ws + off); off += (size_t)4096 * 1024 * 2;   // 8MB
    float*  tab   = (float*)(ws + off);  off += (size_t)4096 * 32 * 2 * 4; // 1MB

    // conversions + RoPE table, one launch (8704 = 8192 cvt + 512 tab blocks)
    k_cvt3<<<8704, 256, 0, stream>>>((const float4*)hs, (const float4*)Wqkv,
                                     (const float4*)Wout, (ushort4*)hsB,
                                     (ushort4*)WqkvB, (ushort4*)WoutB, tab);

    // GEMM1 fused: qkv proj + RoPE + head split + V transpose (128^2 ring, 8 waves)
    k_gemm<1><<<768, 512, 0, stream>>>(hsB, WqkvB, nullptr, pos, tab,
                                       Qh, Kh, Vt, 4096, 3072, 1024, 24);

    // attention: dual q-tile blocks, grid (bh, g)
    k_attn<<<dim3(64, 8), 256, 0, stream>>>(Qh, Kh, Vt, attnB);

    // GEMM2: out projection, f32 output (128^2 ring, 8 waves)
    k_gemm<0><<<256, 512, 0, stream>>>(attnB, WoutB, out, nullptr, nullptr,
                                       nullptr, nullptr, nullptr, 4096, 1024, 1024, 8);
}

// Round 15
// 90.396 us; speedup vs baseline: 1.0950x; 1.0332x over previous
//
#include <hip/hip_runtime.h>

typedef __attribute__((ext_vector_type(8))) short short8;
typedef __attribute__((ext_vector_type(4))) float f32x4;

#define MFMA(a, b, c) __builtin_amdgcn_mfma_f32_16x16x32_bf16((a), (b), (c), 0, 0, 0)

#define S_LEN 1024
#define DM 1024
#define NHEADS 16
#define HD 64
#define NBH 64          // B * NHEADS = 4 * 16
#define MAXPOS 4096

__device__ __forceinline__ ushort f2bf(float f) {
    unsigned u = __builtin_bit_cast(unsigned, f);
    u += 0x7fffu + ((u >> 16) & 1u);
    return (ushort)(u >> 16);
}
__device__ __forceinline__ float bf2f(ushort h) {
    return __builtin_bit_cast(float, (unsigned)h << 16);
}

// async global->LDS, 16B per lane. LDS dest must be base + lane*16 linear.
__device__ __forceinline__ void gload16(const ushort* g, ushort* l) {
    __builtin_amdgcn_global_load_lds(
        (const __attribute__((address_space(1))) unsigned int*)g,
        (__attribute__((address_space(3))) unsigned int*)l, 16, 0, 0);
}

// ------- fp32 -> bf16 conversion (3 tensors) + RoPE table, one launch -------
__global__ __launch_bounds__(256) void k_cvt3(const float4* __restrict__ hs,
                                              const float4* __restrict__ wqkv,
                                              const float4* __restrict__ wout,
                                              ushort4* __restrict__ hsB,
                                              ushort4* __restrict__ wqkvB,
                                              ushort4* __restrict__ woutB,
                                              float* __restrict__ tab) {
    int id = blockIdx.x * 256 + threadIdx.x;
    if (id < 2097152) {
        const float4* src;
        ushort4* dst;
        int off;
        if (id < 1048576)      { src = hs;   dst = hsB;   off = id; }
        else if (id < 1835008) { src = wqkv; dst = wqkvB; off = id - 1048576; }
        else                   { src = wout; dst = woutB; off = id - 1835008; }
        float4 v = src[off];
        ushort4 o;
        o.x = f2bf(v.x); o.y = f2bf(v.y); o.z = f2bf(v.z); o.w = f2bf(v.w);
        dst[off] = o;
    } else {
        int t = id - 2097152;             // 0..131071 = 4096 pos x 32 freq
        int p = t >> 5, i = t & 31;
        float inv = powf(10000.f, -(float)(2 * i) / 64.f);
        float th = (float)p * inv;
        float s, c;
        sincosf(th, &s, &c);
        tab[2 * t] = c;
        tab[2 * t + 1] = s;
    }
}

// ---------------- bf16 GEMM, C = A @ B^T, 128x128 tile, 8 waves (R14) -------
template <int MODE>
__global__ __launch_bounds__(512, 6) void k_gemm(
    const ushort* __restrict__ A, const ushort* __restrict__ BT,
    float* __restrict__ Cf,
    const int* __restrict__ pos, const float* __restrict__ tab,
    ushort* __restrict__ Qh, ushort* __restrict__ Kh, ushort* __restrict__ Vt,
    int M, int N, int K, int nbx) {
    __shared__ __align__(16) ushort SH[3 * 8192];   // 48 KB
    const int tid = threadIdx.x;                 // 0..511
    const int lane = tid & 63, wave = tid >> 6;  // 8 waves
    const int wr = wave >> 2, wc = wave & 3;     // 2 x 4
    const int l15 = lane & 15, lhi = lane >> 4;
    const int nby = gridDim.x / nbx;
    const int xcd = blockIdx.x & 7, idx = blockIdx.x >> 3;
    const int Creg = nbx >> 1, Rreg = nby >> 2;
    const int by = (xcd >> 1) * Rreg + idx / Creg;
    const int bx = (xcd & 1) * Creg + idx % Creg;
    const int m0 = by << 7, n0 = bx << 7;

    const int srow = tid >> 2;                                        // 0..127
    const int scol = (((tid & 3) ^ (srow & 3) ^ ((srow >> 2) & 3)) << 3);
    const int fcol = ((lhi ^ ((l15 & 3) ^ ((l15 >> 2) & 3)))) << 3;

    f32x4 acc[4][2];
#pragma unroll
    for (int i = 0; i < 4; ++i)
#pragma unroll
        for (int j = 0; j < 2; ++j) acc[i][j] = 0;

#define STAGE(bs, kb)                                                           \
    do {                                                                        \
        ushort* bb = SH + (bs) * 8192;                                          \
        gload16(&A[(size_t)(m0 + srow) * K + (kb) + scol], bb + tid * 8);       \
        gload16(&BT[(size_t)(n0 + srow) * K + (kb) + scol],                     \
                bb + 4096 + tid * 8);                                           \
    } while (0)

    const int nk = K >> 5;              // BK = 32
    STAGE(0, 0);
    STAGE(1, 32);
    int bi = 0;
    for (int t = 0; t < nk; ++t) {
        if (t + 1 < nk) {
            asm volatile("s_waitcnt vmcnt(2)" ::: "memory");
        } else {
            asm volatile("s_waitcnt vmcnt(0)" ::: "memory");
        }
        __builtin_amdgcn_s_barrier();
        __builtin_amdgcn_sched_barrier(0);   // pin: nothing crosses the publish point
        if (t + 2 < nk) {
            int bs = bi + 2;
            if (bs >= 3) bs -= 3;
            STAGE(bs, (t + 2) << 5);
        }
        const ushort* bufA = SH + bi * 8192;
        const ushort* bufB = bufA + 4096;
        short8 a[4], b[2];
#pragma unroll
        for (int fm = 0; fm < 4; ++fm)
            a[fm] = *(const short8*)&bufA[(wr * 64 + fm * 16 + l15) * 32 + fcol];
#pragma unroll
        for (int fn = 0; fn < 2; ++fn)
            b[fn] = *(const short8*)&bufB[(wc * 32 + fn * 16 + l15) * 32 + fcol];
#pragma unroll
        for (int fm = 0; fm < 4; ++fm)
#pragma unroll
            for (int fn = 0; fn < 2; ++fn)
                acc[fm][fn] = MFMA(a[fm], b[fn], acc[fm][fn]);
        bi = (bi == 2) ? 0 : bi + 1;
    }
#undef STAGE
    __syncthreads();                    // LDS reuse (V-transpose bounce) safety

    if (MODE == 0) {
#pragma unroll
        for (int fm = 0; fm < 4; ++fm)
#pragma unroll
            for (int fn = 0; fn < 2; ++fn)
#pragma unroll
                for (int i = 0; i < 4; ++i) {
                    int row = m0 + wr * 64 + fm * 16 + lhi * 4 + i;
                    int col = n0 + wc * 32 + fn * 16 + l15;
                    Cf[(size_t)row * N + col] = acc[fm][fn][i];
                }
    } else {
        const int sec = n0 >> 10;                       // 0=q, 1=k, 2=v
        if (sec < 2) {
            ushort* dstb = sec == 0 ? Qh : Kh;
            const float qs = sec == 0 ? 0.125f : 1.0f;
#pragma unroll
            for (int fm = 0; fm < 4; ++fm)
#pragma unroll
                for (int i = 0; i < 4; ++i) {
                    const int row = m0 + wr * 64 + fm * 16 + lhi * 4 + i;
                    const int b = row >> 10, s = row & 1023;
                    int p = pos[s];
                    p = p < 0 ? 0 : (p > MAXPOS - 1 ? MAXPOS - 1 : p);
#pragma unroll
                    for (int fn = 0; fn < 2; ++fn) {
                        const int col = n0 + wc * 32 + fn * 16 + l15;
                        const int cw = col & 1023;
                        const int h = cw >> 6, d = cw & 63;
                        const float c  = tab[((size_t)p * 32 + (d >> 1)) * 2];
                        const float sn = tab[((size_t)p * 32 + (d >> 1)) * 2 + 1];
                        const float v = acc[fm][fn][i];
                        const float pr = __shfl_xor(v, 1);
                        const float o = (d & 1) ? (v * c + pr * sn) : (v * c - pr * sn);
                        dstb[((size_t)((b * 16 + h) * 1024 + s)) * 64 + d] = f2bf(o * qs);
                    }
                }
        } else {
            // V: transpose via LDS bounce (reuse staging buffer), [128][132] pad
            ushort (*T)[132] = (ushort(*)[132]) & SH[0];
#pragma unroll
            for (int fm = 0; fm < 4; ++fm)
#pragma unroll
                for (int fn = 0; fn < 2; ++fn)
#pragma unroll
                    for (int i = 0; i < 4; ++i)
                        T[wr * 64 + fm * 16 + lhi * 4 + i][wc * 32 + fn * 16 + l15] =
                            f2bf(acc[fm][fn][i]);
            __syncthreads();
            const int b = m0 >> 10, s0 = m0 & 1023;
            const int dd = tid & 127, grp = tid >> 7;   // dd: 2 heads x 64 dims
            const int hv = ((n0 & 1023) >> 6) + (dd >> 6);
            const int d = dd & 63;
            ushort* dst = Vt + ((size_t)(b * 16 + hv) * 64 + d) * S_LEN + s0;
#pragma unroll
            for (int j = 0; j < 4; ++j) {
                const int ch = grp * 4 + j;             // 16 chunks of 8 seq
                __align__(16) ushort tmp[8];
#pragma unroll
                for (int e = 0; e < 8; ++e) tmp[e] = T[ch * 8 + e][dd];
                *(uint4*)&dst[ch * 8] = *(uint4*)tmp;
            }
        }
    }
}

// ---------------- flash attention, dual q-tile, KVBLK=128 -------------------
// Block (bh, g): q-tiles A = g, B = 15-g share one staged KV stream of
// 128-key blocks. nkbX = (gX+2)>>1 (tile X active for kb < nkbX); interior
// blocks provably need no causal mask ((nkbX-1)*128 <= gX*64); only the last
// active block uses the masked path. Halves barrier/iteration count vs
// KVBLK=64 at identical MFMA and staging volume. LDS exactly 80 KB ->
// 2 blocks/CU (grid 512 = 2/CU resident anyway, so no occupancy loss).
__global__ __launch_bounds__(256, 2) void k_attn(const ushort* __restrict__ Qh,
                                                 const ushort* __restrict__ Kh,
                                                 const ushort* __restrict__ Vt,
                                                 ushort* __restrict__ attnB) {
    __shared__ __align__(16) ushort Ks[2][128][64];   // 32 KB
    __shared__ __align__(16) ushort Vs[2][64][128];   // 32 KB
    __shared__ __align__(16) ushort P[4][16][128];    // 16 KB  (chunk-XOR swz)
    const int bh = blockIdx.x;
    const int g  = blockIdx.y;                        // 0..7
    const int gA = g, gB = 15 - g;
    const int nkbA = (gA + 2) >> 1;                   // 1..4
    const int nkbB = (gB + 2) >> 1;                   // 5..8
    const int tid = threadIdx.x;
    const int wave = tid >> 6, lane = tid & 63;
    const int l15 = lane & 15, lhi = lane >> 4;
    const int b = bh >> 4, h = bh & 15;
    const ushort* Qp = Qh + (size_t)bh * S_LEN * 64;
    const ushort* Kp = Kh + (size_t)bh * S_LEN * 64;
    const ushort* Vp = Vt + (size_t)bh * 64 * S_LEN;
    const int qbA = (gA << 6) + (wave << 4);
    const int qbB = (gB << 6) + (wave << 4);
    const int qrowbA = qbA + lhi * 4;
    const int qrowbB = qbB + lhi * 4;

    ushort* KsF = &Ks[0][0][0];
    ushort* VsF = &Vs[0][0][0];
    ushort* Pw  = &P[wave][0][0];

    short8 aQA0 = *(const short8*)&Qp[(size_t)(qbA + l15) * 64 + lhi * 8];
    short8 aQA1 = *(const short8*)&Qp[(size_t)(qbA + l15) * 64 + 32 + lhi * 8];
    short8 aQB0 = *(const short8*)&Qp[(size_t)(qbB + l15) * 64 + lhi * 8];
    short8 aQB1 = *(const short8*)&Qp[(size_t)(qbB + l15) * 64 + 32 + lhi * 8];

    short8 ones;
#pragma unroll
    for (int j = 0; j < 8; ++j) ones[j] = (short)0x3F80;   // bf16 1.0

    f32x4 OA0{}, OA1{}, OA2{}, OA3{}, ssumA{};
    f32x4 OB0{}, OB1{}, OB2{}, OB3{}, ssumB{};

    // staging: K = 1024 units (row u>>3 of 128, chunk u&7, swz ^(r&7));
    //          V = 1024 units (row u>>4 of 64 dims, chunk u&15, swz low3 ^(r&7))
#define STAGEKV(bo, k0s)                                                        \
    do {                                                                        \
        _Pragma("unroll") for (int k = 0; k < 4; ++k) {                         \
            const int u = tid + k * 256;                                        \
            const int r = u >> 3, c = u & 7;                                    \
            gload16(&Kp[(size_t)((k0s) + r) * 64 + ((c ^ (r & 7)) << 3)],       \
                    KsF + (bo) + u * 8);                                        \
        }                                                                       \
        _Pragma("unroll") for (int k = 0; k < 4; ++k) {                         \
            const int u = tid + k * 256;                                        \
            const int r = u >> 4, c = u & 15;                                   \
            const int cs = c ^ (r & 7);                                         \
            gload16(&Vp[(size_t)r * S_LEN + (k0s) + cs * 8], VsF + (bo) + u * 8); \
        }                                                                       \
    } while (0)

#define LDSK(s, kk) (*(const short8*)(KsF + (cur << 13) + ((((s) << 4) + l15) << 6) + \
                                      (((((kk) << 2) + lhi) ^ (l15 & 7)) << 3)))
#define LDSV(n, kk) (*(const short8*)(VsF + (cur << 13) + ((((n) << 4) + l15) << 7) + \
                                      (((((kk) << 2) + lhi) ^ (l15 & 7)) << 3)))

    STAGEKV(0, 0);
    __syncthreads();

    int cur = 0;
    for (int kb = 0; kb < nkbB; ++kb) {
        const int k0 = kb << 7;
        if (kb + 1 < nkbB) STAGEKV((cur ^ 1) << 13, k0 + 128);

#define TILE_WORK(AQ0, AQ1, QROWB, NKB, O0, O1, O2, O3, SSUM)                   \
    if (kb < (NKB)) {                                                           \
        f32x4 sc[8];                                                            \
        __builtin_amdgcn_s_setprio(1);                                          \
        _Pragma("unroll") for (int s = 0; s < 8; ++s) {                         \
            sc[s] = f32x4{0.f, 0.f, 0.f, 0.f};                                  \
            sc[s] = MFMA(AQ0, LDSK(s, 0), sc[s]);                               \
            sc[s] = MFMA(AQ1, LDSK(s, 1), sc[s]);                               \
        }                                                                       \
        __builtin_amdgcn_s_setprio(0);                                          \
        if (kb == (NKB) - 1) {                                                  \
            _Pragma("unroll") for (int s = 0; s < 8; ++s)                       \
                _Pragma("unroll") for (int i = 0; i < 4; ++i) {                 \
                    float v = sc[s][i];                                         \
                    if (k0 + s * 16 + l15 > (QROWB) + i) v = -1e30f;            \
                    const int row = lhi * 4 + i;                                \
                    Pw[row * 128 +                                              \
                       (((s * 2 + (l15 >> 3)) ^ (row & 7)) << 3) + (l15 & 7)] = \
                        f2bf(__expf(v - 8.f));                                  \
                }                                                               \
        } else {                                                                \
            _Pragma("unroll") for (int s = 0; s < 8; ++s)                       \
                _Pragma("unroll") for (int i = 0; i < 4; ++i) {                 \
                    const int row = lhi * 4 + i;                                \
                    Pw[row * 128 +                                              \
                       (((s * 2 + (l15 >> 3)) ^ (row & 7)) << 3) + (l15 & 7)] = \
                        f2bf(__expf(sc[s][i] - 8.f));                           \
                }                                                               \
        }                                                                       \
        short8 aP[4];                                                           \
        _Pragma("unroll") for (int kk = 0; kk < 4; ++kk)                        \
            aP[kk] = *(const short8*)&Pw[l15 * 128 +                            \
                                         ((((kk << 2) + lhi) ^ (l15 & 7)) << 3)]; \
        __builtin_amdgcn_s_setprio(1);                                          \
        _Pragma("unroll") for (int kk = 0; kk < 4; ++kk) {                      \
            SSUM = MFMA(aP[kk], ones, SSUM);                                    \
            O0 = MFMA(aP[kk], LDSV(0, kk), O0);                                 \
            O1 = MFMA(aP[kk], LDSV(1, kk), O1);                                 \
            O2 = MFMA(aP[kk], LDSV(2, kk), O2);                                 \
            O3 = MFMA(aP[kk], LDSV(3, kk), O3);                                 \
        }                                                                       \
        __builtin_amdgcn_s_setprio(0);                                          \
    }

        TILE_WORK(aQA0, aQA1, qrowbA, nkbA, OA0, OA1, OA2, OA3, ssumA)
        TILE_WORK(aQB0, aQB1, qrowbB, nkbB, OB0, OB1, OB2, OB3, ssumB)
#undef TILE_WORK

        __syncthreads();
        cur ^= 1;
    }
#undef LDSK
#undef LDSV
#undef STAGEKV

#define WOUT(OV, N, QB, INV)                                                   \
    _Pragma("unroll") for (int i = 0; i < 4; ++i) {                            \
        int row = (QB) + lhi * 4 + i;                                          \
        attnB[((size_t)(b * S_LEN + row)) * DM + h * 64 + (N) * 16 + l15] =    \
            f2bf(OV[i] * INV[i]);                                              \
    }
    {
        f32x4 invA, invB;
#pragma unroll
        for (int i = 0; i < 4; ++i) {
            invA[i] = 1.f / ssumA[i];
            invB[i] = 1.f / ssumB[i];
        }
        WOUT(OA0, 0, qbA, invA) WOUT(OA1, 1, qbA, invA)
        WOUT(OA2, 2, qbA, invA) WOUT(OA3, 3, qbA, invA)
        WOUT(OB0, 0, qbB, invB) WOUT(OB1, 1, qbB, invB)
        WOUT(OB2, 2, qbB, invB) WOUT(OB3, 3, qbB, invB)
    }
#undef WOUT
}

// ---------------------------------------------------------------------------
extern "C" void kernel_launch(void* const* d_in, const int* in_sizes, int n_in,
                              void* d_out, int out_size, void* d_ws, size_t ws_size,
                              hipStream_t stream) {
    (void)in_sizes; (void)n_in; (void)out_size; (void)ws_size;
    const float* hs   = (const float*)d_in[0];
    const int*   pos  = (const int*)d_in[1];
    const float* Wqkv = (const float*)d_in[3];
    const float* Wout = (const float*)d_in[4];
    float* out = (float*)d_out;

    char* ws = (char*)d_ws;
    size_t off = 0;
    ushort* hsB   = (ushort*)(ws + off); off += (size_t)4096 * 1024 * 2;   // 8MB
    ushort* WqkvB = (ushort*)(ws + off); off += (size_t)3072 * 1024 * 2;   // 6MB
    ushort* WoutB = (ushort*)(ws + off); off += (size_t)1024 * 1024 * 2;   // 2MB
    ushort* Qh    = (ushort*)(ws + off); off += (size_t)NBH * 1024 * 64 * 2; // 8MB
    ushort* Kh    = (ushort*)(ws + off); off += (size_t)NBH * 1024 * 64 * 2; // 8MB
    ushort* Vt    = (ushort*)(ws + off); off += (size_t)NBH * 64 * 1024 * 2; // 8MB
    ushort* attnB = (ushort*)(ws + off); off += (size_t)4096 * 1024 * 2;   // 8MB
    float*  tab   = (float*)(ws + off);  off += (size_t)4096 * 32 * 2 * 4; // 1MB

    // conversions + RoPE table, one launch (8704 = 8192 cvt + 512 tab blocks)
    k_cvt3<<<8704, 256, 0, stream>>>((const float4*)hs, (const float4*)Wqkv,
                                     (const float4*)Wout, (ushort4*)hsB,
                                     (ushort4*)WqkvB, (ushort4*)WoutB, tab);

    // GEMM1 fused: qkv proj + RoPE + head split + V transpose (128^2 ring, 8 waves)
    k_gemm<1><<<768, 512, 0, stream>>>(hsB, WqkvB, nullptr, pos, tab,
                                       Qh, Kh, Vt, 4096, 3072, 1024, 24);

    // attention: dual q-tile blocks, KVBLK=128, grid (bh, g)
    k_attn<<<dim3(64, 8), 256, 0, stream>>>(Qh, Kh, Vt, attnB);

    // GEMM2: out projection, f32 output (128^2 ring, 8 waves)
    k_gemm<0><<<256, 512, 0, stream>>>(attnB, WoutB, out, nullptr, nullptr,
                                       nullptr, nullptr, nullptr, 4096, 1024, 1024, 8);
}